// Round 4
// baseline (896.997 us; speedup 1.0000x reference)
//
#include <hip/hip_runtime.h>

#define NN 50000
#define NE 800000

// ws element offsets (4-byte units), 64-aligned; O_EINFO 8B-aligned
#define O_DEGIN   0
#define O_DEGOUT  50048
#define O_ROWPTR  100096
#define O_CURSOR  150208
#define O_EINFO   200256
#define O_FEATN   1800256
#define O_ZF      3400256
#define O_ZNRD    3600320
#define O_VV      3800384
#define O_WDEN    3800832
#define O_YACC    4200896
#define O_H1      17000896
// end 18600896 elems = ~74.4 MB

// ---------------- setup kernels ----------------

__global__ __launch_bounds__(256) void k_deg(const int* __restrict__ src,
                                             const int* __restrict__ dst,
                                             int* degin, int* degout) {
    int e = blockIdx.x * 256 + threadIdx.x;
    if (e < NE) {
        atomicAdd(&degin[dst[e]], 1);
        atomicAdd(&degout[src[e]], 1);
    }
}

__global__ __launch_bounds__(1024) void k_scan(const int* __restrict__ degin,
                                               int* rowptr, int* cursor) {
    __shared__ int sb[1024];
    int t = threadIdx.x;
    int carry = 0;
    for (int ch = 0; ch < 4; ch++) {
        int base = ch * 16384 + t * 16;
        int v[16];
        int s = 0;
#pragma unroll
        for (int j = 0; j < 16; j++) {
            v[j] = (base + j < NN) ? degin[base + j] : 0;
            s += v[j];
        }
        sb[t] = s;
        __syncthreads();
        for (int off = 1; off < 1024; off <<= 1) {
            int x = (t >= off) ? sb[t - off] : 0;
            __syncthreads();
            sb[t] += x;
            __syncthreads();
        }
        int excl = carry + sb[t] - s;
        int tot = sb[1023];
#pragma unroll
        for (int j = 0; j < 16; j++) {
            if (base + j < NN) { rowptr[base + j] = excl; cursor[base + j] = excl; }
            excl += v[j];
        }
        carry += tot;
        __syncthreads();
    }
    if (t == 0) rowptr[NN] = carry;
}

__global__ __launch_bounds__(256) void k_scatter(const int* __restrict__ src,
                                                 const int* __restrict__ dst,
                                                 const int* __restrict__ eid,
                                                 int* cursor, int2* einfo) {
    int e = blockIdx.x * 256 + threadIdx.x;
    if (e >= NE) return;
    int slot = atomicAdd(&cursor[dst[e]], 1);
    einfo[slot] = make_int2(src[e] | (eid[e] << 20), e);
}

// ---------------- per-layer kernels ----------------

// vvec[0:128]=ve[r][k]  (We_r@aw2), [128:256]=vf[r][k] (Wf_r@aw2),
// [256:384]=vd[r][k] (Wd_r@aw2)
__global__ __launch_bounds__(384) void k_prevec(const float* __restrict__ Wr,
                                                const float* __restrict__ attw,
                                                float* __restrict__ vvec) {
    int t = threadIdx.x;
    int r = (t >> 5) & 3, k = t & 31, part = t >> 7;
    int row = (part == 0) ? (32 + k) : (part == 1) ? k : (64 + k);
    const float* wrow = Wr + (size_t)r * 3072 + row * 32;
    float s = 0.f;
#pragma unroll
    for (int c = 0; c < 32; c++) s += wrow[c] * attw[32 + c];
    vvec[t] = s;
}

// One thread per node: featn row, zF[r][n], znrd[r][n] (scalars only)
__global__ __launch_bounds__(256) void k_nodeproj(const float* __restrict__ feat,
                                                  const float* __restrict__ nfeat,
                                                  const float* __restrict__ attw,
                                                  const float* __restrict__ vvec,
                                                  const int* __restrict__ degout,
                                                  float* __restrict__ featn,
                                                  float* __restrict__ zF,
                                                  float* __restrict__ znrd) {
    int n = blockIdx.x * 256 + threadIdx.x;
    if (n >= NN) return;
    int dg = degout[n];
    float sc0 = rsqrtf((float)(dg > 1 ? dg : 1));
    const float* fin = feat + (size_t)n * 32;
    const float* nin = nfeat + (size_t)n * 32;
    float fv[32], nv[32];
#pragma unroll
    for (int k = 0; k < 32; k += 4) {
        float4 f4 = *(const float4*)&fin[k];
        fv[k] = f4.x * sc0; fv[k + 1] = f4.y * sc0;
        fv[k + 2] = f4.z * sc0; fv[k + 3] = f4.w * sc0;
        float4 n4 = *(const float4*)&nin[k];
        nv[k] = n4.x; nv[k + 1] = n4.y; nv[k + 2] = n4.z; nv[k + 3] = n4.w;
    }
    float* fo = featn + (size_t)n * 32;
#pragma unroll
    for (int k = 0; k < 32; k += 4)
        *(float4*)&fo[k] = make_float4(fv[k], fv[k + 1], fv[k + 2], fv[k + 3]);
    float zn = 0.f;
#pragma unroll
    for (int k = 0; k < 32; k++) zn += nv[k] * attw[k];
#pragma unroll
    for (int r = 0; r < 4; r++) {
        float zf = 0.f, zd = 0.f;
        const float* vf = vvec + 128 + r * 32;
        const float* vd = vvec + 256 + r * 32;
#pragma unroll
        for (int k = 0; k < 32; k++) { zf += fv[k] * vf[k]; zd += nv[k] * vd[k]; }
        zF[r * NN + n] = zf;
        znrd[r * NN + n] = zn + zd;
    }
}

// Wave per node. Stage 1 (lane=edge): coalesced einfo + per-lane efeat-row
// dot + one expf for up to 64 edges. Stage 2 (lane=col, 2 edges/iter):
// bpermute broadcast of (ez, s|r, e), raw-row accumulation into 4-relation
// accumulators. Epilogue: half-fold + coalesced yacc/wden store.
__global__ __launch_bounds__(512) void k_fagg(const int* __restrict__ rowptr,
                                              const int2* __restrict__ einfo,
                                              const float* __restrict__ efeat,
                                              const float* __restrict__ featn,
                                              const float* __restrict__ zF,
                                              const float* __restrict__ znrd,
                                              const float* __restrict__ vvec,
                                              float* __restrict__ yacc,
                                              float* __restrict__ wden) {
    __shared__ float sV[128];        // ve[r][k]
    int tid = threadIdx.x;
    if (tid < 128) sV[tid] = vvec[tid];
    __syncthreads();

    int lane = tid & 63;
    int n = blockIdx.x * 8 + (tid >> 6);   // 6250*8 = 50000 exact
    int c = lane & 31;
    int p = lane >> 5;

    int rp0 = rowptr[n];
    int deg = rowptr[n + 1] - rp0;
    float zr0 = znrd[0 * NN + n], zr1 = znrd[1 * NN + n];
    float zr2 = znrd[2 * NN + n], zr3 = znrd[3 * NN + n];

    float yf0 = 0.f, yf1 = 0.f, yf2 = 0.f, yf3 = 0.f;
    float ye0 = 0.f, ye1 = 0.f, ye2 = 0.f, ye3 = 0.f;
    float w0 = 0.f, w1 = 0.f, w2 = 0.f, w3 = 0.f, den = 0.f;

    for (int base = 0; base < deg; base += 64) {
        int cnt = min(64, deg - base);
        // ---- stage 1: lane = edge ----
        int t = lane < cnt ? lane : cnt - 1;
        int2 me = einfo[rp0 + base + t];
        int s1 = me.x & 0xFFFFF;
        int r1 = me.x >> 20;
        const float* er = efeat + (size_t)me.y * 32;
        const float* vr = &sV[r1 * 32];
        float dot = 0.f;
#pragma unroll
        for (int k4 = 0; k4 < 32; k4 += 4) {
            float4 f = *(const float4*)&er[k4];
            float4 v = *(const float4*)&vr[k4];
            dot += f.x * v.x + f.y * v.y + f.z * v.z + f.w * v.w;
        }
        float zrs = (r1 == 0) ? zr0 : (r1 == 1) ? zr1 : (r1 == 2) ? zr2 : zr3;
        float z = zrs + zF[r1 * NN + s1] + dot;
        z = z > 0.f ? z : 0.01f * z;                  // leaky_relu
        float ez = (lane < cnt) ? __expf(z) : 0.f;    // softmax max-shift cancels

        // ---- stage 2: lane = col, 2 edges per iter ----
#pragma unroll 2
        for (int u = 0; u < cnt; u += 2) {
            int sl = u + p;
            float ezb = __shfl(ez, sl);
            int mx = __shfl(me.x, sl);
            int ey = __shfl(me.y, sl);
            int sb = mx & 0xFFFFF;
            int rb = mx >> 20;
            float ef = efeat[(size_t)ey * 32 + c];    // L1/L2 hit (stage-1 warm)
            float fn = featn[(size_t)sb * 32 + c];
            float e0 = (rb == 0) ? ezb : 0.f;
            float e1 = (rb == 1) ? ezb : 0.f;
            float e2 = (rb == 2) ? ezb : 0.f;
            float e3 = (rb == 3) ? ezb : 0.f;
            yf0 += e0 * fn; yf1 += e1 * fn; yf2 += e2 * fn; yf3 += e3 * fn;
            ye0 += e0 * ef; ye1 += e1 * ef; ye2 += e2 * ef; ye3 += e3 * ef;
            w0 += e0; w1 += e1; w2 += e2; w3 += e3;
            den += ezb;
        }
    }

    // fold halves
    yf0 += __shfl_xor(yf0, 32); yf1 += __shfl_xor(yf1, 32);
    yf2 += __shfl_xor(yf2, 32); yf3 += __shfl_xor(yf3, 32);
    ye0 += __shfl_xor(ye0, 32); ye1 += __shfl_xor(ye1, 32);
    ye2 += __shfl_xor(ye2, 32); ye3 += __shfl_xor(ye3, 32);
    w0 += __shfl_xor(w0, 32); w1 += __shfl_xor(w1, 32);
    w2 += __shfl_xor(w2, 32); w3 += __shfl_xor(w3, 32);
    den += __shfl_xor(den, 32);

    // store: yacc[n][j*32+c], j = 4p+jj (half0: yf0..3, half1: ye0..3)
    float* yo = yacc + (size_t)n * 256 + p * 128 + c;
    yo[0]  = p ? ye0 : yf0;
    yo[32] = p ? ye1 : yf1;
    yo[64] = p ? ye2 : yf2;
    yo[96] = p ? ye3 : yf3;
    if (lane < 5) {
        float wv = (lane == 0) ? w0 : (lane == 1) ? w1 : (lane == 2) ? w2
                 : (lane == 3) ? w3 : den;
        wden[n * 8 + lane] = wv;
    }
}

// Half-wave per node: num = u@[Wf|We] + sum_r w_r*(nfeat@Wd_r); h-normalize;
// fused AMRM (+final relu) -> out.
__global__ __launch_bounds__(256) void k_post(const int* __restrict__ rowptr,
                                              const float* __restrict__ yacc,
                                              const float* __restrict__ wden,
                                              const float* __restrict__ nfeat,
                                              const float* __restrict__ Wr,
                                              const float* __restrict__ lw,
                                              const float* __restrict__ hbias,
                                              const float* __restrict__ aW,
                                              const float* __restrict__ ab,
                                              const float* __restrict__ aa,
                                              float* __restrict__ out) {
    int tid = threadIdx.x;
    int c = tid & 31;
    int n = blockIdx.x * 8 + (tid >> 5);   // 6250*8 = 50000 exact

    int deg = rowptr[n + 1] - rowptr[n];
    float den = wden[n * 8 + 4];
    const float* u = yacc + (size_t)n * 256;
    const float* nf = nfeat + (size_t)n * 32;

    float num = 0.f;
#pragma unroll
    for (int r = 0; r < 4; r++) {
        float wr = wden[n * 8 + r];
        const float* W = Wr + (size_t)r * 3072;
        const float* ur = u + r * 32;
#pragma unroll
        for (int k4 = 0; k4 < 32; k4 += 4) {
            float4 uf = *(const float4*)&ur[k4];
            float4 ue = *(const float4*)&ur[128 + k4];
            float4 f4 = *(const float4*)&nf[k4];
            const float* Wk = W + k4 * 32;
            num += uf.x * Wk[c]        + uf.y * Wk[32 + c]
                 + uf.z * Wk[64 + c]   + uf.w * Wk[96 + c];
            num += ue.x * Wk[1024 + c] + ue.y * Wk[1056 + c]
                 + ue.z * Wk[1088 + c] + ue.w * Wk[1120 + c];
            num += wr * (f4.x * Wk[2048 + c] + f4.y * Wk[2080 + c]
                       + f4.z * Wk[2112 + c] + f4.w * Wk[2144 + c]);
        }
    }
    // loopb = nfeat @ loop_w
    float lb = 0.f;
#pragma unroll
    for (int k4 = 0; k4 < 32; k4 += 4) {
        float4 f4 = *(const float4*)&nf[k4];
        const float* Lk = lw + k4 * 32;
        lb += f4.x * Lk[c] + f4.y * Lk[32 + c] + f4.z * Lk[64 + c] + f4.w * Lk[96 + c];
    }
    float h = ((deg > 0) ? num / den : 0.f) + lb;
    h = h * rsqrtf((float)(deg > 1 ? deg : 1)) + hbias[c];

    // AMRM, lane = c: lv_l in regs, h[k] via shfl broadcast
    float a0 = ab[c], a1 = ab[32 + c], a2 = ab[64 + c];
#pragma unroll 8
    for (int k = 0; k < 32; k++) {
        float hk = __shfl(h, k, 32);
        a0 += hk * aW[k * 32 + c];
        a1 += hk * aW[1024 + k * 32 + c];
        a2 += hk * aW[2048 + k * 32 + c];
    }
    float l0 = a0 > 0.f ? a0 : 0.f;
    float l1 = a1 > 0.f ? a1 : 0.f;
    float l2 = a2 > 0.f ? a2 : 0.f;
    float av = aa[c];
    float s0 = l0 * av, s1 = l1 * av, s2 = l2 * av;
#pragma unroll
    for (int off = 16; off > 0; off >>= 1) {
        s0 += __shfl_xor(s0, off, 32);
        s1 += __shfl_xor(s1, off, 32);
        s2 += __shfl_xor(s2, off, 32);
    }
    float mx = fmaxf(s0, fmaxf(s1, s2));
    float e0 = __expf(s0 - mx), e1 = __expf(s1 - mx), e2 = __expf(s2 - mx);
    float inv = 1.f / (e0 + e1 + e2);
    float o = (e0 * l0 + e1 * l1 + e2 * l2) * inv;
    out[(size_t)n * 32 + c] = o > 0.f ? o : 0.f;   // outer relu
}

// ---------------- host ----------------

static void launch_layer(const float* feat, const float* nf, const float* efeat,
                         const float* Wr, const float* attw, const float* lw,
                         const float* hb, const float* aW, const float* ab,
                         const float* aa, float* wsf, int* wsi, float* out,
                         hipStream_t stream) {
    k_prevec<<<1, 384, 0, stream>>>(Wr, attw, wsf + O_VV);
    k_nodeproj<<<196, 256, 0, stream>>>(feat, nf, attw, wsf + O_VV, wsi + O_DEGOUT,
                                        wsf + O_FEATN, wsf + O_ZF, wsf + O_ZNRD);
    k_fagg<<<6250, 512, 0, stream>>>(wsi + O_ROWPTR, (const int2*)(wsi + O_EINFO),
                                     efeat, wsf + O_FEATN, wsf + O_ZF, wsf + O_ZNRD,
                                     wsf + O_VV, wsf + O_YACC, wsf + O_WDEN);
    k_post<<<6250, 256, 0, stream>>>(wsi + O_ROWPTR, wsf + O_YACC, wsf + O_WDEN,
                                     nf, Wr, lw, hb, aW, ab, aa, out);
}

extern "C" void kernel_launch(void* const* d_in, const int* in_sizes, int n_in,
                              void* d_out, int out_size, void* d_ws, size_t ws_size,
                              hipStream_t stream) {
    const float* x     = (const float*)d_in[0];
    const float* nfeat = (const float*)d_in[1];
    const float* efeat = (const float*)d_in[2];
    const int*   src   = (const int*)d_in[3];
    const int*   dst   = (const int*)d_in[4];
    const int*   eid   = (const int*)d_in[5];
    const float* Wr1   = (const float*)d_in[6];
    const float* attw1 = (const float*)d_in[7];
    const float* lw1   = (const float*)d_in[8];
    const float* hb1   = (const float*)d_in[9];
    const float* aW1   = (const float*)d_in[10];
    const float* ab1   = (const float*)d_in[11];
    const float* aa1   = (const float*)d_in[12];
    const float* Wr2   = (const float*)d_in[13];
    const float* attw2 = (const float*)d_in[14];
    const float* lw2   = (const float*)d_in[15];
    const float* hb2   = (const float*)d_in[16];
    const float* aW2   = (const float*)d_in[17];
    const float* ab2   = (const float*)d_in[18];
    const float* aa2   = (const float*)d_in[19];

    float* wsf = (float*)d_ws;
    int*   wsi = (int*)d_ws;
    float* out = (float*)d_out;

    // zero degree counters (degin + degout)
    hipMemsetAsync(d_ws, 0, (size_t)O_ROWPTR * 4, stream);

    k_deg<<<NE / 256, 256, 0, stream>>>(src, dst, wsi + O_DEGIN, wsi + O_DEGOUT);
    k_scan<<<1, 1024, 0, stream>>>(wsi + O_DEGIN, wsi + O_ROWPTR, wsi + O_CURSOR);
    k_scatter<<<NE / 256, 256, 0, stream>>>(src, dst, eid, wsi + O_CURSOR,
                                            (int2*)(wsi + O_EINFO));

    // layer 1: feat = x -> h1 (ws)
    launch_layer(x, nfeat, efeat, Wr1, attw1, lw1, hb1, aW1, ab1, aa1,
                 wsf, wsi, wsf + O_H1, stream);
    // layer 2: feat = h1 -> d_out
    launch_layer(wsf + O_H1, nfeat, efeat, Wr2, attw2, lw2, hb2, aW2, ab2, aa2,
                 wsf, wsi, out, stream);
}

// Round 5
// 731.484 us; speedup vs baseline: 1.2263x; 1.2263x over previous
//
#include <hip/hip_runtime.h>

#define NN 50000
#define NE 800000

// ws element offsets (4-byte units), 64-aligned; O_EINFO 8B-aligned
#define O_DEGIN   0
#define O_DEGOUT  50048
#define O_ROWPTR  100096
#define O_CURSOR  150208
#define O_EINFO   200256
#define O_FEATN   1800256
#define O_ZF      3400256
#define O_ZNRD    3600320
#define O_VV      3800384
#define O_EZ      3800832
#define O_WDEN    4600832
#define O_YACC    5000832
#define O_H1      17800832
// end 19400832 elems = ~77.6 MB

// ---------------- setup kernels ----------------

__global__ __launch_bounds__(256) void k_deg(const int* __restrict__ src,
                                             const int* __restrict__ dst,
                                             int* degin, int* degout) {
    int e = blockIdx.x * 256 + threadIdx.x;
    if (e < NE) {
        atomicAdd(&degin[dst[e]], 1);
        atomicAdd(&degout[src[e]], 1);
    }
}

__global__ __launch_bounds__(1024) void k_scan(const int* __restrict__ degin,
                                               int* rowptr, int* cursor) {
    __shared__ int sb[1024];
    int t = threadIdx.x;
    int carry = 0;
    for (int ch = 0; ch < 4; ch++) {
        int base = ch * 16384 + t * 16;
        int v[16];
        int s = 0;
#pragma unroll
        for (int j = 0; j < 16; j++) {
            v[j] = (base + j < NN) ? degin[base + j] : 0;
            s += v[j];
        }
        sb[t] = s;
        __syncthreads();
        for (int off = 1; off < 1024; off <<= 1) {
            int x = (t >= off) ? sb[t - off] : 0;
            __syncthreads();
            sb[t] += x;
            __syncthreads();
        }
        int excl = carry + sb[t] - s;
        int tot = sb[1023];
#pragma unroll
        for (int j = 0; j < 16; j++) {
            if (base + j < NN) { rowptr[base + j] = excl; cursor[base + j] = excl; }
            excl += v[j];
        }
        carry += tot;
        __syncthreads();
    }
    if (t == 0) rowptr[NN] = carry;
}

__global__ __launch_bounds__(256) void k_scatter(const int* __restrict__ src,
                                                 const int* __restrict__ dst,
                                                 const int* __restrict__ eid,
                                                 int* cursor, int2* einfo) {
    int e = blockIdx.x * 256 + threadIdx.x;
    if (e >= NE) return;
    int slot = atomicAdd(&cursor[dst[e]], 1);
    einfo[slot] = make_int2(src[e] | (eid[e] << 20), e);
}

// ---------------- per-layer kernels ----------------

// vvec[0:128]=ve[r][k] (We_r@aw2), [128:256]=vf[r][k] (Wf_r@aw2),
// [256:384]=vd[r][k] (Wd_r@aw2)
__global__ __launch_bounds__(384) void k_prevec(const float* __restrict__ Wr,
                                                const float* __restrict__ attw,
                                                float* __restrict__ vvec) {
    int t = threadIdx.x;
    int r = (t >> 5) & 3, k = t & 31, part = t >> 7;
    int row = (part == 0) ? (32 + k) : (part == 1) ? k : (64 + k);
    const float* wrow = Wr + (size_t)r * 3072 + row * 32;
    float s = 0.f;
#pragma unroll
    for (int c = 0; c < 32; c++) s += wrow[c] * attw[32 + c];
    vvec[t] = s;
}

// Thread per node: featn row, zF[r][n], znrd[r][n]
__global__ __launch_bounds__(128) void k_nodeproj(const float* __restrict__ feat,
                                                  const float* __restrict__ nfeat,
                                                  const float* __restrict__ attw,
                                                  const float* __restrict__ vvec,
                                                  const int* __restrict__ degout,
                                                  float* __restrict__ featn,
                                                  float* __restrict__ zF,
                                                  float* __restrict__ znrd) {
    int n = blockIdx.x * 128 + threadIdx.x;
    if (n >= NN) return;
    int dg = degout[n];
    float sc0 = rsqrtf((float)(dg > 1 ? dg : 1));
    const float* fin = feat + (size_t)n * 32;
    const float* nin = nfeat + (size_t)n * 32;
    float fv[32], nv[32];
#pragma unroll
    for (int k = 0; k < 32; k += 4) {
        float4 f4 = *(const float4*)&fin[k];
        fv[k] = f4.x * sc0; fv[k + 1] = f4.y * sc0;
        fv[k + 2] = f4.z * sc0; fv[k + 3] = f4.w * sc0;
        float4 n4 = *(const float4*)&nin[k];
        nv[k] = n4.x; nv[k + 1] = n4.y; nv[k + 2] = n4.z; nv[k + 3] = n4.w;
    }
    float* fo = featn + (size_t)n * 32;
#pragma unroll
    for (int k = 0; k < 32; k += 4)
        *(float4*)&fo[k] = make_float4(fv[k], fv[k + 1], fv[k + 2], fv[k + 3]);
    float zn = 0.f;
#pragma unroll
    for (int k = 0; k < 32; k++) zn += nv[k] * attw[k];
#pragma unroll
    for (int r = 0; r < 4; r++) {
        float zf = 0.f, zd = 0.f;
        const float* vf = vvec + 128 + r * 32;
        const float* vd = vvec + 256 + r * 32;
#pragma unroll
        for (int k = 0; k < 32; k++) { zf += fv[k] * vf[k]; zd += nv[k] * vd[k]; }
        zF[r * NN + n] = zf;
        znrd[r * NN + n] = zn + zd;
    }
}

// Flat edge-parallel, original order: ez[e] = exp(leaky(znrd[r][d] + zF[r][s]
// + efeat[e].ve_r)). ve via wave-uniform scalar loads (SGPR operands).
__global__ __launch_bounds__(256) void k_ez(const int* __restrict__ src,
                                            const int* __restrict__ dst,
                                            const int* __restrict__ eid,
                                            const float* __restrict__ efeat,
                                            const float* __restrict__ zF,
                                            const float* __restrict__ znrd,
                                            const float* __restrict__ vvec,
                                            float* __restrict__ ez) {
    int e = blockIdx.x * 256 + threadIdx.x;   // 3125*256 = NE exact
    int s = src[e], d = dst[e], r = eid[e];
    const float* er = efeat + (size_t)e * 32;
    float d0 = 0.f, d1 = 0.f, d2 = 0.f, d3 = 0.f;
#pragma unroll
    for (int k = 0; k < 32; k += 4) {
        float4 f = *(const float4*)&er[k];
        d0 += f.x * vvec[k]       + f.y * vvec[k + 1]
            + f.z * vvec[k + 2]   + f.w * vvec[k + 3];
        d1 += f.x * vvec[32 + k]  + f.y * vvec[33 + k]
            + f.z * vvec[34 + k]  + f.w * vvec[35 + k];
        d2 += f.x * vvec[64 + k]  + f.y * vvec[65 + k]
            + f.z * vvec[66 + k]  + f.w * vvec[67 + k];
        d3 += f.x * vvec[96 + k]  + f.y * vvec[97 + k]
            + f.z * vvec[98 + k]  + f.w * vvec[99 + k];
    }
    float dot = (r == 0) ? d0 : (r == 1) ? d1 : (r == 2) ? d2 : d3;
    float z = znrd[r * NN + d] + zF[r * NN + s] + dot;
    z = z > 0.f ? z : 0.01f * z;      // leaky_relu
    ez[e] = __expf(z);                // softmax max-shift cancels
}

// Wave per node, lane=(p,c): accumulate ez-weighted raw rows into 4-relation
// accumulators. No expf / no reduce chain in loop; low VGPR -> 8 waves/SIMD.
__global__ __launch_bounds__(512) void k_agg(const int* __restrict__ rowptr,
                                             const int2* __restrict__ einfo,
                                             const float* __restrict__ ez,
                                             const float* __restrict__ efeat,
                                             const float* __restrict__ featn,
                                             float* __restrict__ yacc,
                                             float* __restrict__ wden) {
    int tid = threadIdx.x;
    int lane = tid & 63;
    int n = blockIdx.x * 8 + (tid >> 6);   // 6250*8 = 50000 exact
    int c = lane & 31;
    int p = lane >> 5;

    int rp0 = rowptr[n];
    int deg = rowptr[n + 1] - rp0;

    float yf0 = 0.f, yf1 = 0.f, yf2 = 0.f, yf3 = 0.f;
    float ye0 = 0.f, ye1 = 0.f, ye2 = 0.f, ye3 = 0.f;
    float w0 = 0.f, w1 = 0.f, w2 = 0.f, w3 = 0.f, den = 0.f;

    for (int t = p; t < deg; t += 2) {
        int2 me = einfo[rp0 + t];           // broadcast within each half
        int sb = me.x & 0xFFFFF;
        int rb = me.x >> 20;
        float ezv = ez[me.y];
        float ef = efeat[(size_t)me.y * 32 + c];
        float fn = featn[(size_t)sb * 32 + c];
        float e0 = (rb == 0) ? ezv : 0.f;
        float e1 = (rb == 1) ? ezv : 0.f;
        float e2 = (rb == 2) ? ezv : 0.f;
        float e3 = (rb == 3) ? ezv : 0.f;
        yf0 += e0 * fn; yf1 += e1 * fn; yf2 += e2 * fn; yf3 += e3 * fn;
        ye0 += e0 * ef; ye1 += e1 * ef; ye2 += e2 * ef; ye3 += e3 * ef;
        w0 += e0; w1 += e1; w2 += e2; w3 += e3;
        den += ezv;
    }

    // fold halves
    yf0 += __shfl_xor(yf0, 32); yf1 += __shfl_xor(yf1, 32);
    yf2 += __shfl_xor(yf2, 32); yf3 += __shfl_xor(yf3, 32);
    ye0 += __shfl_xor(ye0, 32); ye1 += __shfl_xor(ye1, 32);
    ye2 += __shfl_xor(ye2, 32); ye3 += __shfl_xor(ye3, 32);
    w0 += __shfl_xor(w0, 32); w1 += __shfl_xor(w1, 32);
    w2 += __shfl_xor(w2, 32); w3 += __shfl_xor(w3, 32);
    den += __shfl_xor(den, 32);

    // yacc[n][j*32+c]: half0 -> yf0..3 (j=0..3), half1 -> ye0..3 (j=4..7)
    float* yo = yacc + (size_t)n * 256 + p * 128 + c;
    yo[0]  = p ? ye0 : yf0;
    yo[32] = p ? ye1 : yf1;
    yo[64] = p ? ye2 : yf2;
    yo[96] = p ? ye3 : yf3;
    if (lane < 5) {
        float wv = (lane == 0) ? w0 : (lane == 1) ? w1 : (lane == 2) ? w2
                 : (lane == 3) ? w3 : den;
        wden[n * 8 + lane] = wv;
    }
}

// Thread per node: num = sum_r yf_r@Wf_r + ye_r@We_r + (w_r*nf)@Wd_r;
// + nf@lw; normalize; fused AMRM + relu. All weights wave-uniform -> SGPR.
__global__ __launch_bounds__(128) void k_post(const int* __restrict__ rowptr,
                                              const float* __restrict__ yacc,
                                              const float* __restrict__ wden,
                                              const float* __restrict__ nfeat,
                                              const float* __restrict__ Wr,
                                              const float* __restrict__ lw,
                                              const float* __restrict__ hbias,
                                              const float* __restrict__ aW,
                                              const float* __restrict__ ab,
                                              const float* __restrict__ aa,
                                              float* __restrict__ out) {
    int n = blockIdx.x * 128 + threadIdx.x;
    if (n >= NN) return;
    int deg = rowptr[n + 1] - rowptr[n];
    float den = wden[n * 8 + 4];
    float invden = (deg > 0) ? 1.f / den : 0.f;
    const float* u = yacc + (size_t)n * 256;
    const float* nf = nfeat + (size_t)n * 32;

    float nv[32];
#pragma unroll
    for (int k = 0; k < 32; k += 4) {
        float4 f4 = *(const float4*)&nf[k];
        nv[k] = f4.x; nv[k + 1] = f4.y; nv[k + 2] = f4.z; nv[k + 3] = f4.w;
    }

    float acc[32];
#pragma unroll
    for (int i = 0; i < 32; i++) acc[i] = 0.f;
    for (int r = 0; r < 4; r++) {
        const float* W = Wr + (size_t)r * 3072;
        float wr = wden[n * 8 + r];
        const float* uf = u + r * 32;
        const float* ue = u + 128 + r * 32;
        for (int k4 = 0; k4 < 32; k4 += 4) {
            float4 a4 = *(const float4*)&uf[k4];
            float4 b4 = *(const float4*)&ue[k4];
            float g0 = wr * nv[k4],     g1 = wr * nv[k4 + 1];
            float g2 = wr * nv[k4 + 2], g3 = wr * nv[k4 + 3];
            const float* Wk = W + k4 * 32;
#pragma unroll
            for (int i = 0; i < 32; i++)
                acc[i] += a4.x * Wk[i]        + a4.y * Wk[32 + i]
                        + a4.z * Wk[64 + i]   + a4.w * Wk[96 + i]
                        + b4.x * Wk[1024 + i] + b4.y * Wk[1056 + i]
                        + b4.z * Wk[1088 + i] + b4.w * Wk[1120 + i]
                        + g0 * Wk[2048 + i]   + g1 * Wk[2080 + i]
                        + g2 * Wk[2112 + i]   + g3 * Wk[2144 + i];
        }
    }

    // h = acc/den + nf@lw, scale + bias
    float hsc = rsqrtf((float)(deg > 1 ? deg : 1));
    float h[32];
#pragma unroll
    for (int i = 0; i < 32; i++) h[i] = acc[i] * invden;
    for (int k4 = 0; k4 < 32; k4 += 4) {
        const float* Lk = lw + k4 * 32;
#pragma unroll
        for (int i = 0; i < 32; i++)
            h[i] += nv[k4] * Lk[i] + nv[k4 + 1] * Lk[32 + i]
                  + nv[k4 + 2] * Lk[64 + i] + nv[k4 + 3] * Lk[96 + i];
    }
#pragma unroll
    for (int i = 0; i < 32; i++) h[i] = h[i] * hsc + hbias[i];

    // AMRM pass 1: s_l = sum relu(ab_l + h@aW_l) * aa
    float s[3];
#pragma unroll
    for (int l = 0; l < 3; l++) {
        const float* A = aW + (size_t)l * 1024;
#pragma unroll
        for (int i = 0; i < 32; i++) acc[i] = ab[l * 32 + i];
        for (int k4 = 0; k4 < 32; k4 += 4) {
            const float* Ak = A + k4 * 32;
#pragma unroll
            for (int i = 0; i < 32; i++)
                acc[i] += h[k4] * Ak[i] + h[k4 + 1] * Ak[32 + i]
                        + h[k4 + 2] * Ak[64 + i] + h[k4 + 3] * Ak[96 + i];
        }
        float sl = 0.f;
#pragma unroll
        for (int i = 0; i < 32; i++) {
            float lv = acc[i] > 0.f ? acc[i] : 0.f;
            sl += lv * aa[i];
        }
        s[l] = sl;
    }
    float mx = fmaxf(s[0], fmaxf(s[1], s[2]));
    float e0 = __expf(s[0] - mx), e1 = __expf(s[1] - mx), e2 = __expf(s[2] - mx);
    float inv = 1.f / (e0 + e1 + e2);
    float scl[3] = {e0 * inv, e1 * inv, e2 * inv};

    // AMRM pass 2: out = relu(sum_l scl_l * relu(ab_l + h@aW_l))
    float outv[32];
#pragma unroll
    for (int i = 0; i < 32; i++) outv[i] = 0.f;
#pragma unroll
    for (int l = 0; l < 3; l++) {
        const float* A = aW + (size_t)l * 1024;
#pragma unroll
        for (int i = 0; i < 32; i++) acc[i] = ab[l * 32 + i];
        for (int k4 = 0; k4 < 32; k4 += 4) {
            const float* Ak = A + k4 * 32;
#pragma unroll
            for (int i = 0; i < 32; i++)
                acc[i] += h[k4] * Ak[i] + h[k4 + 1] * Ak[32 + i]
                        + h[k4 + 2] * Ak[64 + i] + h[k4 + 3] * Ak[96 + i];
        }
#pragma unroll
        for (int i = 0; i < 32; i++) {
            float lv = acc[i] > 0.f ? acc[i] : 0.f;
            outv[i] += scl[l] * lv;
        }
    }
    float* op = out + (size_t)n * 32;
#pragma unroll
    for (int i = 0; i < 32; i += 4)
        *(float4*)&op[i] = make_float4(fmaxf(outv[i], 0.f), fmaxf(outv[i + 1], 0.f),
                                       fmaxf(outv[i + 2], 0.f), fmaxf(outv[i + 3], 0.f));
}

// ---------------- host ----------------

static void launch_layer(const float* feat, const float* nf, const float* efeat,
                         const int* src, const int* dst, const int* eid,
                         const float* Wr, const float* attw, const float* lw,
                         const float* hb, const float* aW, const float* ab,
                         const float* aa, float* wsf, int* wsi, float* out,
                         hipStream_t stream) {
    k_prevec<<<1, 384, 0, stream>>>(Wr, attw, wsf + O_VV);
    k_nodeproj<<<391, 128, 0, stream>>>(feat, nf, attw, wsf + O_VV, wsi + O_DEGOUT,
                                        wsf + O_FEATN, wsf + O_ZF, wsf + O_ZNRD);
    k_ez<<<3125, 256, 0, stream>>>(src, dst, eid, efeat, wsf + O_ZF, wsf + O_ZNRD,
                                   wsf + O_VV, wsf + O_EZ);
    k_agg<<<6250, 512, 0, stream>>>(wsi + O_ROWPTR, (const int2*)(wsi + O_EINFO),
                                    wsf + O_EZ, efeat, wsf + O_FEATN,
                                    wsf + O_YACC, wsf + O_WDEN);
    k_post<<<391, 128, 0, stream>>>(wsi + O_ROWPTR, wsf + O_YACC, wsf + O_WDEN,
                                    nf, Wr, lw, hb, aW, ab, aa, out);
}

extern "C" void kernel_launch(void* const* d_in, const int* in_sizes, int n_in,
                              void* d_out, int out_size, void* d_ws, size_t ws_size,
                              hipStream_t stream) {
    const float* x     = (const float*)d_in[0];
    const float* nfeat = (const float*)d_in[1];
    const float* efeat = (const float*)d_in[2];
    const int*   src   = (const int*)d_in[3];
    const int*   dst   = (const int*)d_in[4];
    const int*   eid   = (const int*)d_in[5];
    const float* Wr1   = (const float*)d_in[6];
    const float* attw1 = (const float*)d_in[7];
    const float* lw1   = (const float*)d_in[8];
    const float* hb1   = (const float*)d_in[9];
    const float* aW1   = (const float*)d_in[10];
    const float* ab1   = (const float*)d_in[11];
    const float* aa1   = (const float*)d_in[12];
    const float* Wr2   = (const float*)d_in[13];
    const float* attw2 = (const float*)d_in[14];
    const float* lw2   = (const float*)d_in[15];
    const float* hb2   = (const float*)d_in[16];
    const float* aW2   = (const float*)d_in[17];
    const float* ab2   = (const float*)d_in[18];
    const float* aa2   = (const float*)d_in[19];

    float* wsf = (float*)d_ws;
    int*   wsi = (int*)d_ws;
    float* out = (float*)d_out;

    // zero degree counters (degin + degout)
    hipMemsetAsync(d_ws, 0, (size_t)O_ROWPTR * 4, stream);

    k_deg<<<NE / 256, 256, 0, stream>>>(src, dst, wsi + O_DEGIN, wsi + O_DEGOUT);
    k_scan<<<1, 1024, 0, stream>>>(wsi + O_DEGIN, wsi + O_ROWPTR, wsi + O_CURSOR);
    k_scatter<<<NE / 256, 256, 0, stream>>>(src, dst, eid, wsi + O_CURSOR,
                                            (int2*)(wsi + O_EINFO));

    // layer 1: feat = x -> h1 (ws)
    launch_layer(x, nfeat, efeat, src, dst, eid, Wr1, attw1, lw1, hb1, aW1, ab1, aa1,
                 wsf, wsi, wsf + O_H1, stream);
    // layer 2: feat = h1 -> d_out
    launch_layer(wsf + O_H1, nfeat, efeat, src, dst, eid, Wr2, attw2, lw2, hb2,
                 aW2, ab2, aa2, wsf, wsi, out, stream);
}